// Round 1
// baseline (570.508 us; speedup 1.0000x reference)
//
#include <hip/hip_runtime.h>
#include <hip/hip_bf16.h>
#include <stdint.h>

// GATv2: A=128, S=64, P=16, F=128, H=4, D=128.
// Inputs f32; OUTPUTS f32 (threshold = 2% rel, no bf16-eps floor -> f32 readback).
// MFMA in bf16 with hi/lo splits for X, G, P; only W's bf16 rounding remains.
// R1: PV loop restructured kb-outer (P-frag pressure 32->8 VGPRs) to eliminate
//     scratch spills under the 128-VGPR cap from __launch_bounds__(512,4).

typedef short short8 __attribute__((ext_vector_type(8)));
typedef float f32x4 __attribute__((ext_vector_type(4)));

__device__ __forceinline__ float bf2f(unsigned short u) {
    return __uint_as_float(((unsigned int)u) << 16);
}
__device__ __forceinline__ unsigned short f2bf(float f) {
    unsigned int x = __float_as_uint(f);
    return (unsigned short)((x + 0x7FFFu + ((x >> 16) & 1u)) >> 16);
}
__device__ __forceinline__ float lrelu(float x) {
    return fmaxf(x, 0.2f * x);   // valid for slope in (0,1): max(x,0.2x) == leaky_relu
}

// Precompute: Wt[hd][f] = bf16(W_r[f][hd])  (B-operand, W^T)
//             V_l[h][f] = sum_d W_l[f][h*128+d] * w_attn[d]      (f32 exact)
//             V_r[h][f] = sum_d W_r[f][h*128+d] * w_attn[128+d]  (f32 exact)
__global__ void gat_precomp(const float* __restrict__ Wl,
                            const float* __restrict__ Wr,
                            const float* __restrict__ wattn,
                            unsigned short* __restrict__ Wt,
                            float* __restrict__ Vl,
                            float* __restrict__ Vr) {
    int b = blockIdx.x, t = threadIdx.x;
    if (b < 64) {
        int base = b * 1024 + t * 4;          // linear index into W_r (F x 512)
        float4 v = *(const float4*)(Wr + base);
        int f = base >> 9;
        int c = base & 511;                   // hd
        Wt[(c + 0) * 128 + f] = f2bf(v.x);
        Wt[(c + 1) * 128 + f] = f2bf(v.y);
        Wt[(c + 2) * 128 + f] = f2bf(v.z);
        Wt[(c + 3) * 128 + f] = f2bf(v.w);
    } else {
        const float* W  = (b == 64) ? Wl : Wr;
        const float* aw = wattn + ((b == 64) ? 0 : 128);
        float* V = (b == 64) ? Vl : Vr;
        for (int r = 0; r < 2; ++r) {
            int o = t + r * 256;
            int f = o >> 2, hh = o & 3;
            float acc = 0.f;
            for (int d = 0; d < 128; ++d)
                acc += W[f * 512 + hh * 128 + d] * aw[d];
            V[hh * 128 + f] = acc;
        }
    }
}

// One block per (s,p). 512 threads = 8 waves; wave w owns a 16-row strip.
__global__ __launch_bounds__(512, 4)
void gat_main(const float* __restrict__ hin,
              const unsigned short* __restrict__ Wt,
              const float* __restrict__ Vl,
              const float* __restrict__ Vr,
              float* __restrict__ out_attn,
              float* __restrict__ out_a) {
    // Phase A: XG[0]=X_hi, XG[1]=X_lo (bf16 planes of staged h rows).
    // Phase B (head loop): XG[0]=G_hi, XG[1]=G_lo, transposed [d][j].
    __shared__ __align__(16) unsigned short XG[2][128][136];
    __shared__ float sLs[4][128];
    __shared__ float sRs[4][128];
    __shared__ float Ms[4][128];
    __shared__ float Siv[4][128];

    const int sp = blockIdx.x;                // sp = s*16 + p
    const int t = threadIdx.x;

    // ---- 1. stage X: f32 h rows -> bf16 hi/lo planes
    #pragma unroll
    for (int k = 0; k < 8; ++k) {
        int c = k * 512 + t;                  // 4096 chunks of 4 floats
        int a = c >> 5, cc = c & 31;
        float4 v = *(const float4*)(hin + (size_t)a * 131072 + sp * 128 + cc * 4);
        ushort4 uh, ul;
        uh.x = f2bf(v.x); ul.x = f2bf(v.x - bf2f(uh.x));
        uh.y = f2bf(v.y); ul.y = f2bf(v.y - bf2f(uh.y));
        uh.z = f2bf(v.z); ul.z = f2bf(v.z - bf2f(uh.z));
        uh.w = f2bf(v.w); ul.w = f2bf(v.w - bf2f(uh.w));
        *(ushort4*)(&XG[0][a][cc * 4]) = uh;
        *(ushort4*)(&XG[1][a][cc * 4]) = ul;
    }
    __syncthreads();

    // ---- 2. s_l[a][h] = x . V_l[h], s_r likewise (x = hi+lo, ~exact f32)
    {
        int a = t >> 2, hh = t & 3;
        float al = 0.f, ar = 0.f;
        for (int f = 0; f < 128; f += 4) {
            ushort4 xh = *(const ushort4*)(&XG[0][a][f]);
            ushort4 xl = *(const ushort4*)(&XG[1][a][f]);
            float4 vl = *(const float4*)(Vl + hh * 128 + f);
            float4 vr = *(const float4*)(Vr + hh * 128 + f);
            float x0 = bf2f(xh.x) + bf2f(xl.x);
            float x1 = bf2f(xh.y) + bf2f(xl.y);
            float x2 = bf2f(xh.z) + bf2f(xl.z);
            float x3 = bf2f(xh.w) + bf2f(xl.w);
            al += x0 * vl.x + x1 * vl.y + x2 * vl.z + x3 * vl.w;
            ar += x0 * vr.x + x1 * vr.y + x2 * vr.z + x3 * vr.w;
        }
        sLs[hh][a] = al;
        sRs[hh][a] = ar;
    }
    __syncthreads();

    // ---- 3. per-(i,h) row max and sum (diagonal excluded)
    {
        int i = t >> 2, hh = t & 3;
        float sr = sRs[hh][i];
        float m = -1e30f;
        for (int j = 0; j < 128; ++j) {
            if (j == i) continue;
            float e = lrelu(sr + sLs[hh][j]);
            m = fmaxf(m, e);
        }
        float sum = 0.f;
        for (int j = 0; j < 128; ++j) {
            if (j == i) continue;
            float e = lrelu(sr + sLs[hh][j]);
            sum += __expf(e - m);
        }
        Ms[hh][i] = m;
        Siv[hh][i] = 1.f / sum;
    }
    __syncthreads();

    const int w = t >> 6;       // wave id 0..7
    const int l = t & 63;
    const int q = l >> 4;       // quad 0..3
    const int ln = l & 15;

    // A fragments of X rows 16w..16w+15 (hi/lo), hoisted: X identical across heads.
    // Must be read before the head loop's first barrier (Gs overwrites these planes).
    short8 axh[4], axl[4];
    #pragma unroll
    for (int kb = 0; kb < 4; ++kb) {
        axh[kb] = *(const short8*)(&XG[0][16 * w + ln][32 * kb + 8 * q]);
        axl[kb] = *(const short8*)(&XG[1][16 * w + ln][32 * kb + 8 * q]);
    }

    // ---- 4. write attention weights a[s,p,i,j,h] as f32 (float4, coalesced)
    {
        float* oa = out_a + (size_t)sp * 65536;
        for (int k = 0; k < 32; ++k) {
            int idx = k * 512 + t;
            int i = idx >> 7, j = idx & 127;
            float4 r4;
            float* rp = (float*)&r4;
            #pragma unroll
            for (int hh = 0; hh < 4; ++hh) {
                float pv = 0.f;
                if (j != i) {
                    float e = lrelu(sRs[hh][i] + sLs[hh][j]);
                    pv = __expf(e - Ms[hh][i]) * Siv[hh][i];
                }
                rp[hh] = pv;
            }
            *(float4*)(oa + (size_t)idx * 4) = r4;
        }
    }

    // ---- 5. head loop: G_h = X @ W_h (2-term); attn += P_h @ G_h (3-term)
    f32x4 acc[8];
    #pragma unroll
    for (int tj = 0; tj < 8; ++tj) acc[tj] = (f32x4){0.f, 0.f, 0.f, 0.f};

    for (int hh = 0; hh < 4; ++hh) {
        __syncthreads();  // all afrag/X reads + previous head's Gs reads complete

        #pragma unroll
        for (int tj = 0; tj < 8; ++tj) {
            f32x4 g = (f32x4){0.f, 0.f, 0.f, 0.f};
            #pragma unroll
            for (int kb = 0; kb < 4; ++kb) {
                // B-frag: B[k=8q+j][n=ln] = Wt[hd=16tj+ln][f=32kb+8q+j] (L2-hot)
                short8 bh = *(const short8*)(Wt + ((hh * 128 + 16 * tj + ln) * 128 + 32 * kb + 8 * q));
                g = __builtin_amdgcn_mfma_f32_16x16x32_bf16(axh[kb], bh, g, 0, 0, 0);
                g = __builtin_amdgcn_mfma_f32_16x16x32_bf16(axl[kb], bh, g, 0, 0, 0);
            }
            // C layout: row a = 16w+4q+r, col d = 16tj+ln. Store G^T hi/lo: Gs[d][a].
            ushort4 gh4, gl4;
            unsigned short* ghp = (unsigned short*)&gh4;
            unsigned short* glp = (unsigned short*)&gl4;
            #pragma unroll
            for (int r = 0; r < 4; ++r) {
                float v = g[r];
                unsigned short hb = f2bf(v);
                ghp[r] = hb;
                glp[r] = f2bf(v - bf2f(hb));
            }
            *(ushort4*)(&XG[0][16 * tj + ln][16 * w + 4 * q]) = gh4;
            *(ushort4*)(&XG[1][16 * tj + ln][16 * w + 4 * q]) = gl4;
        }
        __syncthreads();

        // PV: kb-outer so only ONE P-fragment pair (8 VGPRs) is live at a time.
        // Per-acc[tj] accumulation order is unchanged (kb 0..3, 3 terms each).
        {
            const int i = 16 * w + ln;
            const float sr = sRs[hh][i];
            const float m = Ms[hh][i];
            const float si = Siv[hh][i];
            #pragma unroll 1
            for (int kb = 0; kb < 4; ++kb) {
                short8 ph, pl;
                #pragma unroll
                for (int jj = 0; jj < 8; ++jj) {
                    int j = 32 * kb + 8 * q + jj;
                    float pv = 0.f;
                    if (j != i) {
                        float e = lrelu(sr + sLs[hh][j]);
                        pv = __expf(e - m) * si;
                    }
                    unsigned short hb = f2bf(pv);
                    ph[jj] = (short)hb;
                    pl[jj] = (short)f2bf(pv - bf2f(hb));
                }
                #pragma unroll
                for (int tj = 0; tj < 8; ++tj) {
                    short8 bh = *(const short8*)(&XG[0][16 * tj + ln][32 * kb + 8 * q]);
                    short8 bl = *(const short8*)(&XG[1][16 * tj + ln][32 * kb + 8 * q]);
                    acc[tj] = __builtin_amdgcn_mfma_f32_16x16x32_bf16(ph, bh, acc[tj], 0, 0, 0);
                    acc[tj] = __builtin_amdgcn_mfma_f32_16x16x32_bf16(ph, bl, acc[tj], 0, 0, 0);
                    acc[tj] = __builtin_amdgcn_mfma_f32_16x16x32_bf16(pl, bh, acc[tj], 0, 0, 0);
                }
            }
        }
    }

    // ---- 6. epilogue: attn_res[a][sp][d] = 0.25 * acc, f32
    #pragma unroll
    for (int tj = 0; tj < 8; ++tj) {
        int d = 16 * tj + ln;
        #pragma unroll
        for (int r = 0; r < 4; ++r) {
            int i = 16 * w + 4 * q + r;
            out_attn[((size_t)i * 1024 + sp) * 128 + d] = acc[tj][r] * 0.25f;
        }
    }
}

extern "C" void kernel_launch(void* const* d_in, const int* in_sizes, int n_in,
                              void* d_out, int out_size, void* d_ws, size_t ws_size,
                              hipStream_t stream) {
    const float* hin   = (const float*)d_in[0];
    const float* Wl    = (const float*)d_in[1];
    const float* Wr    = (const float*)d_in[2];
    const float* wattn = (const float*)d_in[3];

    unsigned short* Wt = (unsigned short*)d_ws;                    // 65536 bf16 = 128 KiB
    float* Vl = (float*)((char*)d_ws + 131072);                    // 512 f32
    float* Vr = (float*)((char*)d_ws + 131072 + 2048);             // 512 f32

    float* out_attn = (float*)d_out;                               // 16,777,216 f32
    float* out_a    = (float*)d_out + 16777216;                    // 67,108,864 f32

    gat_precomp<<<66, 256, 0, stream>>>(Wl, Wr, wattn, Wt, Vl, Vr);
    gat_main<<<1024, 512, 0, stream>>>(hin, Wt, Vl, Vr, out_attn, out_a);
}

// Round 4
// 550.106 us; speedup vs baseline: 1.0371x; 1.0371x over previous
//
#include <hip/hip_runtime.h>
#include <hip/hip_bf16.h>
#include <stdint.h>

// GATv2: A=128, S=64, P=16, F=128, H=4, D=128.
// Inputs f32; OUTPUTS f32. MFMA bf16.
// R2 (third submission; two infra failures, never yet benched): occupancy package.
//  - G stored as SINGLE bf16 plane (drop G_lo): LDS 77824 -> ~43.3 KB -> 3 blocks/CU.
//  - X never staged in LDS: s_l/s_r dots read f32 h from global (exact),
//    A-fragments built from global per head (L2-hot; reloaded to cap VGPR<=85 for 6 w/EU).
//  - Softmax max-pass removed exactly via lrelu monotonicity (per-head top-2 of s_l).
//  - Stats arrays padded [4][132] to kill 4-way same-bank conflicts.
//  - PV: 2 MFMA per step (P_hi,P_lo x G_hi). P stays hi/lo (out_a accuracy preserved).

typedef short short8 __attribute__((ext_vector_type(8)));
typedef float f32x4 __attribute__((ext_vector_type(4)));

__device__ __forceinline__ float bf2f(unsigned short u) {
    return __uint_as_float(((unsigned int)u) << 16);
}
__device__ __forceinline__ unsigned short f2bf(float f) {
    unsigned int x = __float_as_uint(f);
    return (unsigned short)((x + 0x7FFFu + ((x >> 16) & 1u)) >> 16);
}
__device__ __forceinline__ float lrelu(float x) {
    return fmaxf(x, 0.2f * x);   // slope in (0,1): max(x,0.2x) == leaky_relu, monotone
}

// Precompute: Wt[hd][f] = bf16(W_r[f][hd])  (B-operand, W^T)
//             V_l[h][f] = sum_d W_l[f][h*128+d] * w_attn[d]      (f32 exact)
//             V_r[h][f] = sum_d W_r[f][h*128+d] * w_attn[128+d]  (f32 exact)
__global__ void gat_precomp(const float* __restrict__ Wl,
                            const float* __restrict__ Wr,
                            const float* __restrict__ wattn,
                            unsigned short* __restrict__ Wt,
                            float* __restrict__ Vl,
                            float* __restrict__ Vr) {
    int b = blockIdx.x, t = threadIdx.x;
    if (b < 64) {
        int base = b * 1024 + t * 4;          // linear index into W_r (F x 512)
        float4 v = *(const float4*)(Wr + base);
        int f = base >> 9;
        int c = base & 511;                   // hd
        Wt[(c + 0) * 128 + f] = f2bf(v.x);
        Wt[(c + 1) * 128 + f] = f2bf(v.y);
        Wt[(c + 2) * 128 + f] = f2bf(v.z);
        Wt[(c + 3) * 128 + f] = f2bf(v.w);
    } else {
        const float* W  = (b == 64) ? Wl : Wr;
        const float* aw = wattn + ((b == 64) ? 0 : 128);
        float* V = (b == 64) ? Vl : Vr;
        for (int r = 0; r < 2; ++r) {
            int o = t + r * 256;
            int f = o >> 2, hh = o & 3;
            float acc = 0.f;
            for (int d = 0; d < 128; ++d)
                acc += W[f * 512 + hh * 128 + d] * aw[d];
            V[hh * 128 + f] = acc;
        }
    }
}

// One block per (s,p). 512 threads = 8 waves; wave w owns a 16-row strip.
__global__ __launch_bounds__(512, 6)
void gat_main(const float* __restrict__ hin,
              const unsigned short* __restrict__ Wt,
              const float* __restrict__ Vl,
              const float* __restrict__ Vr,
              float* __restrict__ out_attn,
              float* __restrict__ out_a) {
    __shared__ __align__(16) unsigned short Gs[128][136];  // G_hi, transposed [d][j]
    __shared__ float sLs[4][132];
    __shared__ float sRs[4][132];
    __shared__ float Ms[4][132];
    __shared__ float Siv[4][132];
    __shared__ float mx1[4], mx2[4];
    __shared__ int   ax1[4];

    const int sp = blockIdx.x;                // sp = s*16 + p
    const int t = threadIdx.x;
    const int w = t >> 6;                     // wave id 0..7
    const int l = t & 63;
    const int q = l >> 4;                     // quad 0..3
    const int ln = l & 15;

    // ---- A. s_l[a][h] = h_row . V_l[h], s_r likewise — f32 exact from global
    {
        int a = t >> 2, hh = t & 3;
        const float* hr = hin + (size_t)a * 131072 + sp * 128;
        const float* vl = Vl + hh * 128;
        const float* vr = Vr + hh * 128;
        float al = 0.f, ar = 0.f;
        for (int f = 0; f < 128; f += 4) {
            float4 x  = *(const float4*)(hr + f);
            float4 a4 = *(const float4*)(vl + f);
            float4 b4 = *(const float4*)(vr + f);
            al += x.x * a4.x + x.y * a4.y + x.z * a4.z + x.w * a4.w;
            ar += x.x * b4.x + x.y * b4.y + x.z * b4.z + x.w * b4.w;
        }
        sLs[hh][a] = al;
        sRs[hh][a] = ar;
    }
    __syncthreads();

    // ---- B. per-head top-2 (value,argmax) of s_l — replaces the 128-iter max pass.
    // Exact: lrelu monotone => max_{j!=i} lrelu(sR+sL[j]) = lrelu(sR + max_{j!=i} sL[j]).
    if (w < 4) {
        float v0 = sLs[w][l], v1 = sLs[w][l + 64];
        float m1, m2; int a1;
        if (v0 >= v1) { m1 = v0; m2 = v1; a1 = l; }
        else          { m1 = v1; m2 = v0; a1 = l + 64; }
        #pragma unroll
        for (int off = 32; off; off >>= 1) {
            float o1 = __shfl_down(m1, off);
            float o2 = __shfl_down(m2, off);
            int   ob = __shfl_down(a1, off);
            if (o1 > m1) { m2 = fmaxf(m1, o2); m1 = o1; a1 = ob; }
            else         { m2 = fmaxf(m2, o1); }
        }
        if (l == 0) { mx1[w] = m1; mx2[w] = m2; ax1[w] = a1; }
    }
    __syncthreads();

    // ---- C. per-(i,h): m from top-2, then sum pass (diag handled by subtraction)
    {
        int i = t >> 2, hh = t & 3;
        float sr = sRs[hh][i];
        float Mi = (i == ax1[hh]) ? mx2[hh] : mx1[hh];
        float m = lrelu(sr + Mi);
        float sum = 0.f;
        for (int j = 0; j < 128; ++j) {
            float e = lrelu(sr + sLs[hh][j]);
            sum += __expf(e - m);
        }
        sum -= __expf(lrelu(sr + sLs[hh][i]) - m);   // remove diagonal term
        Ms[hh][i] = m;
        Siv[hh][i] = 1.f / sum;
    }
    __syncthreads();

    // ---- D. write attention weights a[s,p,i,j,h] as f32 (float4, coalesced)
    {
        float* oa = out_a + (size_t)sp * 65536;
        for (int k = 0; k < 32; ++k) {
            int idx = k * 512 + t;
            int i = idx >> 7, j = idx & 127;
            float4 r4;
            float* rp = (float*)&r4;
            #pragma unroll
            for (int hh = 0; hh < 4; ++hh) {
                float pv = 0.f;
                if (j != i) {
                    float e = lrelu(sRs[hh][i] + sLs[hh][j]);
                    pv = __expf(e - Ms[hh][i]) * Siv[hh][i];
                }
                rp[hh] = pv;
            }
            *(float4*)(oa + (size_t)idx * 4) = r4;
        }
    }

    // ---- E. head loop: G_h = X @ W_h (X bf16-hi from global); attn += P_h @ G_h
    f32x4 acc[8];
    #pragma unroll
    for (int tj = 0; tj < 8; ++tj) acc[tj] = (f32x4){0.f, 0.f, 0.f, 0.f};

    const float* hrw = hin + (size_t)(16 * w + ln) * 131072 + sp * 128;

    for (int hh = 0; hh < 4; ++hh) {
        __syncthreads();  // previous head's Gs reads complete before overwrite

        // A-fragments of X rows (bf16 hi), reloaded per head to cap VGPR (L1/L2-hot)
        short8 axh[4];
        #pragma unroll
        for (int kb = 0; kb < 4; ++kb) {
            float4 xa = *(const float4*)(hrw + 32 * kb + 8 * q);
            float4 xb = *(const float4*)(hrw + 32 * kb + 8 * q + 4);
            short8 v;
            v[0] = (short)f2bf(xa.x); v[1] = (short)f2bf(xa.y);
            v[2] = (short)f2bf(xa.z); v[3] = (short)f2bf(xa.w);
            v[4] = (short)f2bf(xb.x); v[5] = (short)f2bf(xb.y);
            v[6] = (short)f2bf(xb.z); v[7] = (short)f2bf(xb.w);
            axh[kb] = v;
        }

        #pragma unroll
        for (int tj = 0; tj < 8; ++tj) {
            f32x4 g = (f32x4){0.f, 0.f, 0.f, 0.f};
            #pragma unroll
            for (int kb = 0; kb < 4; ++kb) {
                // B-frag: B[k=8q+j][n=ln] = Wt[hd=16tj+ln][f=32kb+8q+j] (L2-hot)
                short8 bh = *(const short8*)(Wt + ((hh * 128 + 16 * tj + ln) * 128 + 32 * kb + 8 * q));
                g = __builtin_amdgcn_mfma_f32_16x16x32_bf16(axh[kb], bh, g, 0, 0, 0);
            }
            // C layout: row a = 16w+4q+r, col d = 16tj+ln. Store G^T hi: Gs[d][a].
            ushort4 gh4;
            unsigned short* ghp = (unsigned short*)&gh4;
            #pragma unroll
            for (int r = 0; r < 4; ++r) ghp[r] = f2bf(g[r]);
            *(ushort4*)(&Gs[16 * tj + ln][16 * w + 4 * q]) = gh4;
        }
        __syncthreads();

        // PV: kb-outer, one P hi/lo pair live at a time; 2 MFMA per (kb,tj).
        {
            const int i = 16 * w + ln;
            const float sr = sRs[hh][i];
            const float m = Ms[hh][i];
            const float si = Siv[hh][i];
            #pragma unroll 1
            for (int kb = 0; kb < 4; ++kb) {
                short8 ph, pl;
                #pragma unroll
                for (int jj = 0; jj < 8; ++jj) {
                    int j = 32 * kb + 8 * q + jj;
                    float pv = 0.f;
                    if (j != i) {
                        float e = lrelu(sr + sLs[hh][j]);
                        pv = __expf(e - m) * si;
                    }
                    unsigned short hb = f2bf(pv);
                    ph[jj] = (short)hb;
                    pl[jj] = (short)f2bf(pv - bf2f(hb));
                }
                #pragma unroll
                for (int tj = 0; tj < 8; ++tj) {
                    short8 bh = *(const short8*)(&Gs[16 * tj + ln][32 * kb + 8 * q]);
                    acc[tj] = __builtin_amdgcn_mfma_f32_16x16x32_bf16(ph, bh, acc[tj], 0, 0, 0);
                    acc[tj] = __builtin_amdgcn_mfma_f32_16x16x32_bf16(pl, bh, acc[tj], 0, 0, 0);
                }
            }
        }
    }

    // ---- F. epilogue: attn_res[a][sp][d] = 0.25 * acc, f32
    #pragma unroll
    for (int tj = 0; tj < 8; ++tj) {
        int d = 16 * tj + ln;
        #pragma unroll
        for (int r = 0; r < 4; ++r) {
            int i = 16 * w + 4 * q + r;
            out_attn[((size_t)i * 1024 + sp) * 128 + d] = acc[tj][r] * 0.25f;
        }
    }
}

extern "C" void kernel_launch(void* const* d_in, const int* in_sizes, int n_in,
                              void* d_out, int out_size, void* d_ws, size_t ws_size,
                              hipStream_t stream) {
    const float* hin   = (const float*)d_in[0];
    const float* Wl    = (const float*)d_in[1];
    const float* Wr    = (const float*)d_in[2];
    const float* wattn = (const float*)d_in[3];

    unsigned short* Wt = (unsigned short*)d_ws;                    // 65536 bf16 = 128 KiB
    float* Vl = (float*)((char*)d_ws + 131072);                    // 512 f32
    float* Vr = (float*)((char*)d_ws + 131072 + 2048);             // 512 f32

    float* out_attn = (float*)d_out;                               // 16,777,216 f32
    float* out_a    = (float*)d_out + 16777216;                    // 67,108,864 f32

    gat_precomp<<<66, 256, 0, stream>>>(Wl, Wr, wattn, Wt, Vl, Vr);
    gat_main<<<1024, 512, 0, stream>>>(hin, Wt, Vl, Vr, out_attn, out_a);
}